// Round 8
// baseline (10327.231 us; speedup 1.0000x reference)
//
#include <hip/hip_runtime.h>
#include <stdint.h>

typedef _Float16 f16;
typedef __attribute__((ext_vector_type(8))) _Float16 f16x8;
typedef __attribute__((ext_vector_type(4))) float f32x4;

#define TT 512
#define FF 3
#define HH 128
#define BB 16384
#define BC 32          // batch rows per block -> 512 blocks, 1 per CU (LDS-forced), 2 rounds
#define PITCH 296      // hc row pitch in f16 (592 B = 37 x 16B slots, odd -> 2-way banks max)
#define NTH 512        // 8 waves, col-split (16 cols x 4 gates each), m=2
#define WP 40          // wlds row pitch in f16 (80 B)

// Packed weights: Bp[grp(13)][gate(4)][col(128)][ksub(4)][e(8)] f16
//   grp 0..4  : layer0, K=160 (128 h0 + 3 data + ZERO delta-col + 28 zero)
//   grp 5..12 : layer1, K=256 (128 h0' + 128 h1)
// Runtime: groups 0..9 in registers (160 VGPR), groups 10..12 in LDS.
// delta enters G0 as a rank-1 VALU update (weights col k=131 zeroed in prep).
#define NGRP 13
#define GSTRIDE 16384
#define NBP (NGRP*GSTRIDE)
#define WS_BIAS_OFF ((size_t)NBP*2)

__global__ void prep_kernel(
    const float* __restrict__ Wih0, const float* __restrict__ Whh0,
    const float* __restrict__ bih0, const float* __restrict__ bhh0,
    const float* __restrict__ Wih1, const float* __restrict__ Whh1,
    const float* __restrict__ bih1, const float* __restrict__ bhh1,
    f16* __restrict__ Bp, float* __restrict__ biasSum)
{
  int idx = blockIdx.x*256 + threadIdx.x;
  if (idx < NBP){
    int e = idx & 7, ksub = (idx>>3)&3, c = (idx>>5)&127, g = (idx>>12)&3, grp = idx>>14;
    int kl = ksub*8 + e;               // 0..31 within group
    int gcol = g*128 + c;              // row of W (4H)
    float v = 0.f;
    if (grp < 5){
      int k = grp*32 + kl;             // 0..159
      if (k < 128)      v = Whh0[gcol*128 + k];
      else if (k < 131) v = Wih0[gcol*4 + (k - 128)];  // data0..2; k=131 (delta) stays 0
    } else {
      int k = (grp-5)*32 + kl;         // 0..255
      v = (k < 128) ? Wih1[gcol*128 + k] : Whh1[gcol*128 + (k - 128)];
    }
    Bp[idx] = (f16)v;
  } else if (idx < NBP + 1024){
    int j = idx - NBP;
    int layer = j >> 9, gcol = j & 511;
    biasSum[j] = layer ? (bih1[gcol] + bhh1[gcol]) : (bih0[gcol] + bhh0[gcol]);
  }
}

// fused LSTM element update: returns h, updates c in place. 5 exp + 2 rcp.
// No input clamps: |preact| < 15 guaranteed by weight scale (STD=1/sqrt(128)).
__device__ __forceinline__ float cell_elem(float iv, float fv, float gv, float ov, float& cs){
  float ea = __expf(-iv);
  float eb = __expf(2.f*gv);
  float ef = __expf(-fv);
  float A = 1.f + ea, Bq = 1.f + eb, F = 1.f + ef;
  float AB  = A*Bq;
  float num = cs*AB + (eb - 1.f)*F;
  float c   = num * __builtin_amdgcn_rcpf(AB*F);
  cs = c;
  float cc = fminf(fmaxf(c, -15.f), 15.f);    // exp(2c) overflow guard only
  float ew = __expf(2.f*cc);
  float eo = __expf(-ov);
  return (ew - 1.f) * __builtin_amdgcn_rcpf((1.f + eo)*(1.f + ew));  // sig(o)*tanh(c)
}

__global__ __launch_bounds__(NTH)
void lstm_kernel(
    const float* __restrict__ data, const float* __restrict__ PnL,
    const f16*  __restrict__ Bp,   const float* __restrict__ biasSum,
    const float* __restrict__ fcW, const float* __restrict__ fcb,
    const int* __restrict__ ploc,  const float* __restrict__ Wih0,
    float* __restrict__ out)
{
  // hc cols: [0,128) h0 | [128,256) h1 | [256,259) x | [259,296) zero
  __shared__ __align__(16) f16 hc[2*BC*PITCH];        // 37,888 B
  __shared__ __align__(16) f16 wlds[3*512*WP];        // 122,880 B (groups 10..12)
  __shared__ float fcw_s[HH];                          // 512 B
  __shared__ float dbuf[BC][16];                       // 2,048 B
  __shared__ float pnlbuf[BC];                         // 128 B
  __shared__ float dcol[BC];                           // 128 B (f32 delta broadcast)
  // total 163,584 B -> 1 block/CU -> 2 waves/SIMD -> 256-reg budget

  const int tid = threadIdx.x;
  const int w   = tid >> 6;
  const int l   = tid & 63;
  const int l15 = l & 15;
  const int lhi = l >> 4;
  const int jc  = w*16 + l15;      // owned gate-column 0..127
  const int bg0 = blockIdx.x * BC;

  for (int i = tid; i < 2*BC*PITCH; i += NTH) hc[i] = (f16)0.f;
  if (tid < HH) fcw_s[tid] = fcW[tid];

  for (int i = tid; i < 3*4*128*4; i += NTH){
    int ksub = i & 3, col = (i>>2)&127, g = (i>>9)&3, grp3 = i>>11;
    *(f16x8*)&wlds[((grp3*512) + g*128 + col)*WP + ksub*8] =
      *(const f16x8*)(Bp + (10+grp3)*GSTRIDE + g*4096 + col*32 + ksub*8);
  }

  float bias0[4], bias1[4], wd[4];
#pragma unroll
  for (int g = 0; g < 4; ++g){
    bias0[g] = biasSum[g*HH + jc];
    bias1[g] = biasSum[512 + g*HH + jc];
    wd[g]    = Wih0[(g*128 + jc)*4 + 3];   // delta-column weight (rank-1 path)
  }
  const float fcb0 = fcb[0];
  const int   pl   = ploc[0];

  // persistent weights: groups 0..9 -> 160 VGPR
  f16x8 wr[10][4];
  {
    const f16* BpL = Bp + jc*32 + lhi*8;
#pragma unroll
    for (int grp = 0; grp < 10; ++grp)
#pragma unroll
      for (int g = 0; g < 4; ++g)
        wr[grp][g] = *(const f16x8*)(BpL + grp*GSTRIDE + g*4096);
  }

  __syncthreads();
  // stage x(0) into hc[0].x
  if (tid < 128 && (tid & 3))
    hc[(tid>>2)*PITCH + 255 + (tid&3)] = (f16)data[(size_t)(bg0 + (tid>>2))*TT*FF + (tid&3) - 1];
  if (tid < BC) __builtin_nontemporal_store(0.f, &out[(size_t)(bg0 + tid)*513]);

  const int rowD = tid >> 4;
  const int subD = tid & 15;
  float fcw_r[8];
#pragma unroll
  for (int u = 0; u < 8; ++u) fcw_r[u] = fcw_s[subD*8 + u];

  float cs0[8], cs1[8];
#pragma unroll
  for (int e = 0; e < 8; ++e){ cs0[e] = 0.f; cs1[e] = 0.f; }
  float pnl = 0.f, dold = 0.f;

  __syncthreads();

  // ===== prologue: layer0 step 0 (h0(-1)=0, delta(-1)=0 -> only x-part MFMA) =====
  {
    f32x4 acc0[2][4];
#pragma unroll
    for (int g = 0; g < 4; ++g){
      f32x4 v = {bias0[g], bias0[g], bias0[g], bias0[g]};
      acc0[0][g] = v; acc0[1][g] = v;
    }
    const int colA = 256 + 8*lhi;
#pragma unroll
    for (int m = 0; m < 2; ++m){
      f16x8 a = *(const f16x8*)&hc[(m*16 + l15)*PITCH + colA];
#pragma unroll
      for (int g = 0; g < 4; ++g)
        acc0[m][g] = __builtin_amdgcn_mfma_f32_16x16x32_f16(a, wr[4][g], acc0[m][g], 0, 0, 0);
    }
#pragma unroll
    for (int m = 0; m < 2; ++m)
#pragma unroll
      for (int r = 0; r < 4; ++r){
        float h = cell_elem(acc0[m][0][r], acc0[m][1][r], acc0[m][2][r], acc0[m][3][r], cs0[m*4+r]);
        hc[(m*16 + lhi*4 + r)*PITCH + jc] = (f16)h;   // h0(0) -> Ab(0)=hc[0]
      }
  }
  __syncthreads();   // B1: h0(0) visible

  // ===== main loop: iter k = layer1(k) + delta(k) + layer0(k+1) =====
  for (int k = 0; k < TT-1; ++k){
    f16* Ab = &hc[(k & 1) * (BC*PITCH)];        // h0(k), h1(k-1)
    f16* Qb = &hc[((k & 1) ^ 1) * (BC*PITCH)];  // receives h1(k), x(k+1), h0(k+1)

    if (k && (k & 15) == 0)
      __builtin_nontemporal_store(dbuf[rowD][subD],
          &out[(size_t)(bg0 + rowD)*513 + (k - 15) + subD]);

    float price_r = 0.f;
    if (subD == 0)
      price_r = data[(size_t)((bg0 + rowD)*TT + k)*FF + pl];
    float xnv = 0.f;
    const bool do_stage = (tid < 128) && (tid & 3);
    if (do_stage)
      xnv = data[(size_t)((bg0 + (tid>>2))*TT + (k+1))*FF + (tid&3) - 1];

    // ---- G1(k): [h0(k), h1(k-1)] @ W1^T + b  (all A-reads from Ab) ----
    f32x4 acc1[2][4];
#pragma unroll
    for (int g = 0; g < 4; ++g){
      f32x4 v = {bias1[g], bias1[g], bias1[g], bias1[g]};
      acc1[0][g] = v; acc1[1][g] = v;
    }
#pragma unroll
    for (int ks = 0; ks < 8; ++ks){
      const int colA = ks*32 + 8*lhi;
      f16x8 a0 = *(const f16x8*)&Ab[(l15)*PITCH + colA];
      f16x8 a1 = *(const f16x8*)&Ab[(16 + l15)*PITCH + colA];
#pragma unroll
      for (int g = 0; g < 4; ++g){
        f16x8 bf;
        if (ks < 5) bf = wr[5 + ks][g];
        else        bf = *(const f16x8*)&wlds[(((ks-5)*512) + g*128 + jc)*WP + lhi*8];
        acc1[0][g] = __builtin_amdgcn_mfma_f32_16x16x32_f16(a0, bf, acc1[0][g], 0, 0, 0);
        acc1[1][g] = __builtin_amdgcn_mfma_f32_16x16x32_f16(a1, bf, acc1[1][g], 0, 0, 0);
      }
    }

    // ---- cell1(k) -> Qb.h1 ----
#pragma unroll
    for (int m = 0; m < 2; ++m)
#pragma unroll
      for (int r = 0; r < 4; ++r){
        float h = cell_elem(acc1[m][0][r], acc1[m][1][r], acc1[m][2][r], acc1[m][3][r], cs1[m*4+r]);
        Qb[(m*16 + lhi*4 + r)*PITCH + 128 + jc] = (f16)h;
      }

    // stage x(k+1) into Qb.x (read by G0 after B2)
    if (do_stage)
      Qb[(tid>>2)*PITCH + 255 + (tid&3)] = (f16)xnv;
    __syncthreads();   // B2: h1(k), x(k+1) visible

    // ---- G0(k+1) MFMAs (h0(k) + data part; delta col zeroed) — issued first,
    //      drain overlaps the delta-phase VALU below ----
    f32x4 acc0[2][4];
#pragma unroll
    for (int g = 0; g < 4; ++g){
      f32x4 v = {bias0[g], bias0[g], bias0[g], bias0[g]};
      acc0[0][g] = v; acc0[1][g] = v;
    }
#pragma unroll
    for (int ks = 0; ks < 5; ++ks){
      const int colA = (ks < 4 ? ks*32 : 256) + 8*lhi;
      const f16* ap = (ks < 4) ? Ab : Qb;     // h0(k) from Ab; x(k+1) from Qb
#pragma unroll
      for (int m = 0; m < 2; ++m){
        f16x8 a = *(const f16x8*)&ap[(m*16 + l15)*PITCH + colA];
#pragma unroll
        for (int g = 0; g < 4; ++g)
          acc0[m][g] = __builtin_amdgcn_mfma_f32_16x16x32_f16(a, wr[ks][g], acc0[m][g], 0, 0, 0);
      }
    }

    // ---- delta(k): h1(k) @ fcW^T + fcb (VALU/LDS, overlaps G0 drain) ----
    {
      f16x8 v = *(const f16x8*)&Qb[rowD*PITCH + 128 + subD*8];
      float s = 0.f;
#pragma unroll
      for (int u = 0; u < 8; ++u) s += (float)v[u] * fcw_r[u];
      s += __shfl_xor(s, 1);
      s += __shfl_xor(s, 2);
      s += __shfl_xor(s, 4);
      s += __shfl_xor(s, 8);
      if (subD == 0){
        const float dnew = s + fcb0;
        pnl += (dold - dnew) * price_r;
        dbuf[rowD][k & 15] = dnew;
        dcol[rowD] = dnew;
        dold = dnew;
      }
    }
    __syncthreads();   // B3: dcol visible

    // ---- rank-1 delta term + cell0(k+1) -> Qb.h0 ----
#pragma unroll
    for (int m = 0; m < 2; ++m)
#pragma unroll
      for (int r = 0; r < 4; ++r){
        const float dd = dcol[m*16 + lhi*4 + r];
        float h = cell_elem(acc0[m][0][r] + dd*wd[0],
                            acc0[m][1][r] + dd*wd[1],
                            acc0[m][2][r] + dd*wd[2],
                            acc0[m][3][r] + dd*wd[3], cs0[m*4+r]);
        Qb[(m*16 + lhi*4 + r)*PITCH + jc] = (f16)h;
      }
    __syncthreads();   // B1: Qb complete -> becomes Ab
  }

  // ===== tail: k = TT-1 (layer1 + delta + pnl only) =====
  {
    const int k = TT-1;
    f16* Ab = &hc[(k & 1) * (BC*PITCH)];
    f16* Qb = &hc[((k & 1) ^ 1) * (BC*PITCH)];
    float price_r = 0.f;
    if (subD == 0)
      price_r = data[(size_t)((bg0 + rowD)*TT + k)*FF + pl];

    f32x4 acc1[2][4];
#pragma unroll
    for (int g = 0; g < 4; ++g){
      f32x4 v = {bias1[g], bias1[g], bias1[g], bias1[g]};
      acc1[0][g] = v; acc1[1][g] = v;
    }
#pragma unroll
    for (int ks = 0; ks < 8; ++ks){
      const int colA = ks*32 + 8*lhi;
      f16x8 a0 = *(const f16x8*)&Ab[(l15)*PITCH + colA];
      f16x8 a1 = *(const f16x8*)&Ab[(16 + l15)*PITCH + colA];
#pragma unroll
      for (int g = 0; g < 4; ++g){
        f16x8 bf;
        if (ks < 5) bf = wr[5 + ks][g];
        else        bf = *(const f16x8*)&wlds[(((ks-5)*512) + g*128 + jc)*WP + lhi*8];
        acc1[0][g] = __builtin_amdgcn_mfma_f32_16x16x32_f16(a0, bf, acc1[0][g], 0, 0, 0);
        acc1[1][g] = __builtin_amdgcn_mfma_f32_16x16x32_f16(a1, bf, acc1[1][g], 0, 0, 0);
      }
    }
#pragma unroll
    for (int m = 0; m < 2; ++m)
#pragma unroll
      for (int r = 0; r < 4; ++r){
        float h = cell_elem(acc1[m][0][r], acc1[m][1][r], acc1[m][2][r], acc1[m][3][r], cs1[m*4+r]);
        Qb[(m*16 + lhi*4 + r)*PITCH + 128 + jc] = (f16)h;
      }
    __syncthreads();

    {
      f16x8 v = *(const f16x8*)&Qb[rowD*PITCH + 128 + subD*8];
      float s = 0.f;
#pragma unroll
      for (int u = 0; u < 8; ++u) s += (float)v[u] * fcw_r[u];
      s += __shfl_xor(s, 1);
      s += __shfl_xor(s, 2);
      s += __shfl_xor(s, 4);
      s += __shfl_xor(s, 8);
      if (subD == 0){
        const float dnew = s + fcb0;
        pnl += (dold - dnew) * price_r;
        dbuf[rowD][k & 15] = dnew;
        const float lastp = data[(size_t)((bg0 + rowD)*TT + (TT-1))*FF + 0];
        pnlbuf[rowD] = pnl + dnew*lastp;
      }
    }
    __syncthreads();
  }

  __builtin_nontemporal_store(dbuf[rowD][subD],
      &out[(size_t)(bg0 + rowD)*513 + 497 + subD]);
  if (tid < BC)
    out[(size_t)BB*513 + bg0 + tid] = pnlbuf[tid] + PnL[bg0 + tid];
}

extern "C" void kernel_launch(void* const* d_in, const int* in_sizes, int n_in,
                              void* d_out, int out_size, void* d_ws, size_t ws_size,
                              hipStream_t stream)
{
  const float* data = (const float*)d_in[0];
  const float* PnL  = (const float*)d_in[1];
  const float* Wih0 = (const float*)d_in[2];
  const float* Whh0 = (const float*)d_in[3];
  const float* bih0 = (const float*)d_in[4];
  const float* bhh0 = (const float*)d_in[5];
  const float* Wih1 = (const float*)d_in[6];
  const float* Whh1 = (const float*)d_in[7];
  const float* bih1 = (const float*)d_in[8];
  const float* bhh1 = (const float*)d_in[9];
  const float* fcW  = (const float*)d_in[10];
  const float* fcb  = (const float*)d_in[11];
  const int*   ploc = (const int*)d_in[12];

  f16*   Bp      = (f16*)d_ws;
  float* biasSum = (float*)((char*)d_ws + WS_BIAS_OFF);
  float* out     = (float*)d_out;

  const int prepN = NBP + 1024;
  prep_kernel<<<(prepN + 255)/256, 256, 0, stream>>>(
      Wih0, Whh0, bih0, bhh0, Wih1, Whh1, bih1, bhh1, Bp, biasSum);
  lstm_kernel<<<BB/BC, NTH, 0, stream>>>(
      data, PnL, Bp, biasSum, fcW, fcb, ploc, Wih0, out);
}

// Round 9
// 8126.736 us; speedup vs baseline: 1.2708x; 1.2708x over previous
//
#include <hip/hip_runtime.h>
#include <stdint.h>

typedef _Float16 f16;
typedef __attribute__((ext_vector_type(8))) _Float16 f16x8;
typedef __attribute__((ext_vector_type(4))) float f32x4;

#define TT 512
#define FF 3
#define HH 128
#define BB 16384
#define BC 32          // batch rows per block -> 512 blocks, 1 per CU (LDS-forced), 2 rounds
#define PITCH 296      // hc row pitch in f16 (148 dw, mod 32 = 20 -> 2-way banks on A-frag reads)
#define NTH 512        // 8 waves, col-split (16 cols x 4 gates each), m=2
#define WP 40          // wlds row pitch in f16

// Packed weights: Bp[grp(13)][gate(4)][col(128)][ksub(4)][e(8)] f16
//   grp 0..4  : layer0, K=160 (128 h0 + 3 data + ZERO delta col + 28 zero)
//   grp 5..12 : layer1, K=256 (128 h0' + 128 h1)
// groups 0..9 in registers (160 VGPR), 10..12 in LDS. delta enters via rank-1 (wd).
#define NGRP 13
#define GSTRIDE 16384
#define NBP (NGRP*GSTRIDE)
#define WS_BIAS_OFF ((size_t)NBP*2)

__global__ void prep_kernel(
    const float* __restrict__ Wih0, const float* __restrict__ Whh0,
    const float* __restrict__ bih0, const float* __restrict__ bhh0,
    const float* __restrict__ Wih1, const float* __restrict__ Whh1,
    const float* __restrict__ bih1, const float* __restrict__ bhh1,
    f16* __restrict__ Bp, float* __restrict__ biasSum)
{
  int idx = blockIdx.x*256 + threadIdx.x;
  if (idx < NBP){
    int e = idx & 7, ksub = (idx>>3)&3, c = (idx>>5)&127, g = (idx>>12)&3, grp = idx>>14;
    int kl = ksub*8 + e;
    int gcol = g*128 + c;
    float v = 0.f;
    if (grp < 5){
      int k = grp*32 + kl;             // 0..159
      if (k < 128)      v = Whh0[gcol*128 + k];
      else if (k < 131) v = Wih0[gcol*4 + (k - 128)];  // data0..2; k=131 (delta) stays 0
    } else {
      int k = (grp-5)*32 + kl;         // 0..255
      v = (k < 128) ? Wih1[gcol*128 + k] : Whh1[gcol*128 + (k - 128)];
    }
    Bp[idx] = (f16)v;
  } else if (idx < NBP + 1024){
    int j = idx - NBP;
    int layer = j >> 9, gcol = j & 511;
    biasSum[j] = layer ? (bih1[gcol] + bhh1[gcol]) : (bih0[gcol] + bhh0[gcol]);
  }
}

// fused LSTM element update: returns h, updates c in place. 5 exp + 2 rcp.
__device__ __forceinline__ float cell_elem(float iv, float fv, float gv, float ov, float& cs){
  float ea = __expf(-iv);
  float eb = __expf(2.f*gv);
  float ef = __expf(-fv);
  float A = 1.f + ea, Bq = 1.f + eb, F = 1.f + ef;
  float AB  = A*Bq;
  float num = cs*AB + (eb - 1.f)*F;
  float c   = num * __builtin_amdgcn_rcpf(AB*F);
  cs = c;
  float cc = fminf(fmaxf(c, -15.f), 15.f);
  float ew = __expf(2.f*cc);
  float eo = __expf(-ov);
  return (ew - 1.f) * __builtin_amdgcn_rcpf((1.f + eo)*(1.f + ew));
}

__global__ __launch_bounds__(NTH)
void lstm_kernel(
    const float* __restrict__ data, const float* __restrict__ PnL,
    const f16*  __restrict__ Bp,   const float* __restrict__ biasSum,
    const float* __restrict__ fcW, const float* __restrict__ fcb,
    const int* __restrict__ ploc,  const float* __restrict__ Wih0,
    float* __restrict__ out)
{
  // hc cols: [0,128) h0 | [128,256) h1 | [256,259) x | [259,296) zero
  __shared__ __align__(16) f16 hc[2*BC*PITCH];        // 37,888 B
  __shared__ __align__(16) f16 wlds[3*512*WP];        // 122,880 B
  __shared__ float fcw_s[HH];                          // 512 B
  __shared__ float dbuf[BC][16];                       // 2,048 B
  __shared__ float pnlbuf[BC];                         // 128 B
  // total 163,456 B -> 1 block/CU -> 2 waves/SIMD -> 256-reg budget

  const int tid = threadIdx.x;
  const int w   = tid >> 6;
  const int l   = tid & 63;
  const int l15 = l & 15;
  const int lhi = l >> 4;
  const int jc  = w*16 + l15;
  const int bg0 = blockIdx.x * BC;

  for (int i = tid; i < 2*BC*PITCH; i += NTH) hc[i] = (f16)0.f;
  if (tid < HH) fcw_s[tid] = fcW[tid];

  for (int i = tid; i < 3*4*128*4; i += NTH){
    int ksub = i & 3, col = (i>>2)&127, g = (i>>9)&3, grp3 = i>>11;
    *(f16x8*)&wlds[((grp3*512) + g*128 + col)*WP + ksub*8] =
      *(const f16x8*)(Bp + (10+grp3)*GSTRIDE + g*4096 + col*32 + ksub*8);
  }

  float bias0[4], bias1[4], wd[4];
#pragma unroll
  for (int g = 0; g < 4; ++g){
    bias0[g] = biasSum[g*HH + jc];
    bias1[g] = biasSum[512 + g*HH + jc];
    wd[g]    = Wih0[(g*128 + jc)*4 + 3];   // delta-column weight (rank-1 path)
  }
  const float fcb0 = fcb[0];
  const int   pl   = ploc[0];

  // persistent weights: groups 0..9 -> 160 VGPR
  f16x8 wr[10][4];
  {
    const f16* BpL = Bp + jc*32 + lhi*8;
#pragma unroll
    for (int grp = 0; grp < 10; ++grp)
#pragma unroll
      for (int g = 0; g < 4; ++g)
        wr[grp][g] = *(const f16x8*)(BpL + grp*GSTRIDE + g*4096);
  }

  __syncthreads();
  // stage x(0) into hc[0].x
  if (tid < 128 && (tid & 3))
    hc[(tid>>2)*PITCH + 255 + (tid&3)] = (f16)data[(size_t)(bg0 + (tid>>2))*TT*FF + (tid&3) - 1];
  if (tid < BC) __builtin_nontemporal_store(0.f, &out[(size_t)(bg0 + tid)*513]);

  float cs0[8], cs1[8];
#pragma unroll
  for (int e = 0; e < 8; ++e){ cs0[e] = 0.f; cs1[e] = 0.f; }
  float pnl = 0.f, dold = 0.f, ddv = 0.f;

  __syncthreads();

  // ===== prologue: cell0(0) (h0(-1)=0, delta(-1)=0 -> x-part MFMA only) =====
  {
    f32x4 acc[2][4];
#pragma unroll
    for (int g = 0; g < 4; ++g){
      f32x4 v = {bias0[g], bias0[g], bias0[g], bias0[g]};
      acc[0][g] = v; acc[1][g] = v;
    }
    const int colA = 256 + 8*lhi;
#pragma unroll
    for (int m = 0; m < 2; ++m){
      f16x8 a = *(const f16x8*)&hc[(m*16 + l15)*PITCH + colA];
#pragma unroll
      for (int g = 0; g < 4; ++g)
        acc[m][g] = __builtin_amdgcn_mfma_f32_16x16x32_f16(a, wr[4][g], acc[m][g], 0, 0, 0);
    }
#pragma unroll
    for (int m = 0; m < 2; ++m)
#pragma unroll
      for (int r = 0; r < 4; ++r){
        float h = cell_elem(acc[m][0][r], acc[m][1][r], acc[m][2][r], acc[m][3][r], cs0[m*4+r]);
        hc[(m*16 + lhi*4 + r)*PITCH + jc] = (f16)h;   // h0(0) -> hc[0]
      }
  }
  __syncthreads();
  // stage x(1) into hc[0].x (x(0) fully consumed above)
  if (tid < 128 && (tid & 3))
    hc[(tid>>2)*PITCH + 255 + (tid&3)] = (f16)data[(size_t)((bg0 + (tid>>2))*TT + 1)*FF + (tid&3) - 1];
  __syncthreads();   // iter-0 state ready in hc[0]

  // ===== main loop: iter k = G1(k), cell1(k), B2, [G0(k+1) || delta(k)], cell0(k+1), B1 =====
  for (int k = 0; k < TT-1; ++k){
    f16* Rb = &hc[(k & 1) * (BC*PITCH)];        // h0(k), h1(k-1), x(k+1)
    f16* Qb = &hc[((k & 1) ^ 1) * (BC*PITCH)];  // receives h1(k), h0(k+1), x(k+2)

    if (k && !(k & 15))
      __builtin_nontemporal_store(dbuf[tid>>4][tid&15],
          &out[(size_t)(bg0 + (tid>>4))*513 + (k - 15) + (tid&15)]);

    float price_r = 0.f;
    if (w == 0 && l < 32)
      price_r = data[(size_t)((bg0 + l)*TT + k)*FF + pl];
    float xnv = 0.f;
    const bool do_stage = (k < TT-2) && (tid < 128) && (tid & 3);
    if (do_stage)
      xnv = data[(size_t)((bg0 + (tid>>2))*TT + (k+2))*FF + (tid&3) - 1];

    // ---- G1(k): [h0(k), h1(k-1)] @ W1^T + b  (all A-frags from Rb) ----
    {
      f32x4 acc[2][4];
#pragma unroll
      for (int g = 0; g < 4; ++g){
        f32x4 v = {bias1[g], bias1[g], bias1[g], bias1[g]};
        acc[0][g] = v; acc[1][g] = v;
      }
#pragma unroll
      for (int ks = 0; ks < 8; ++ks){
        const int colA = ks*32 + 8*lhi;
        f16x8 a0 = *(const f16x8*)&Rb[(l15)*PITCH + colA];
        f16x8 a1 = *(const f16x8*)&Rb[(16 + l15)*PITCH + colA];
#pragma unroll
        for (int g = 0; g < 4; ++g){
          f16x8 bf;
          if (ks < 5) bf = wr[5 + ks][g];
          else        bf = *(const f16x8*)&wlds[(((ks-5)*512) + g*128 + jc)*WP + lhi*8];
          acc[0][g] = __builtin_amdgcn_mfma_f32_16x16x32_f16(a0, bf, acc[0][g], 0, 0, 0);
          acc[1][g] = __builtin_amdgcn_mfma_f32_16x16x32_f16(a1, bf, acc[1][g], 0, 0, 0);
        }
      }
      // cell1(k) -> Qb.h1
#pragma unroll
      for (int m = 0; m < 2; ++m)
#pragma unroll
        for (int r = 0; r < 4; ++r){
          float h = cell_elem(acc[m][0][r], acc[m][1][r], acc[m][2][r], acc[m][3][r], cs1[m*4+r]);
          Qb[(m*16 + lhi*4 + r)*PITCH + 128 + jc] = (f16)h;
        }
    }
    __syncthreads();   // B2: h1(k) visible

    // ---- G0(k+1) MFMAs issued first (matrix pipe), delta(k) VALU hides under them ----
    {
      f32x4 acc[2][4];
#pragma unroll
      for (int g = 0; g < 4; ++g){
        f32x4 v = {bias0[g], bias0[g], bias0[g], bias0[g]};
        acc[0][g] = v; acc[1][g] = v;
      }
#pragma unroll
      for (int ks = 0; ks < 5; ++ks){
        const int colA = (ks < 4 ? ks*32 : 256) + 8*lhi;   // h0(k) / x(k+1), all in Rb
#pragma unroll
        for (int m = 0; m < 2; ++m){
          f16x8 a = *(const f16x8*)&Rb[(m*16 + l15)*PITCH + colA];
#pragma unroll
          for (int g = 0; g < 4; ++g)
            acc[m][g] = __builtin_amdgcn_mfma_f32_16x16x32_f16(a, wr[ks][g], acc[m][g], 0, 0, 0);
        }
      }

      // delta(k): every wave computes all 32 rows redundantly (lane owns row l&31, half l>>5)
      {
        const int dof = (l >> 5) * 64;
        const f16*  hp = &Qb[(l & 31)*PITCH + 128 + dof];
        const float* fp = &fcw_s[dof];
        float s0 = 0.f, s1 = 0.f;
#pragma unroll
        for (int c = 0; c < 4; ++c){
          f16x8 hv = *(const f16x8*)(hp + c*16);
          f16x8 gv = *(const f16x8*)(hp + c*16 + 8);
#pragma unroll
          for (int u = 0; u < 8; ++u){
            s0 += (float)hv[u] * fp[c*16 + u];
            s1 += (float)gv[u] * fp[c*16 + 8 + u];
          }
        }
        float s = s0 + s1;
        s += __shfl_xor(s, 32);
        ddv = s + fcb0;                 // delta(k), identical in all lanes' row-slot
      }

      // cell0(k+1): rank-1 delta term via in-wave broadcast
#pragma unroll
      for (int m = 0; m < 2; ++m)
#pragma unroll
        for (int r = 0; r < 4; ++r){
          const float dd = __shfl(ddv, m*16 + lhi*4 + r);
          float h = cell_elem(acc[m][0][r] + dd*wd[0],
                              acc[m][1][r] + dd*wd[1],
                              acc[m][2][r] + dd*wd[2],
                              acc[m][3][r] + dd*wd[3], cs0[m*4+r]);
          Qb[(m*16 + lhi*4 + r)*PITCH + jc] = (f16)h;
        }
    }

    // stage x(k+2) -> Qb.x ; wave0 bookkeeping
    if (do_stage)
      Qb[(tid>>2)*PITCH + 255 + (tid&3)] = (f16)xnv;
    if (w == 0 && l < 32){
      pnl += (dold - ddv) * price_r;
      dbuf[l][k & 15] = ddv;
      dold = ddv;
    }
    __syncthreads();   // B1: Qb complete -> becomes Rb
  }

  // ===== tail: k = TT-1 (G1 + cell1 + delta + pnl) =====
  {
    const int k = TT-1;
    f16* Rb = &hc[(k & 1) * (BC*PITCH)];
    f16* Qb = &hc[((k & 1) ^ 1) * (BC*PITCH)];
    float price_r = 0.f, lastp = 0.f;
    if (w == 0 && l < 32){
      price_r = data[(size_t)((bg0 + l)*TT + k)*FF + pl];
      lastp   = data[(size_t)((bg0 + l)*TT + (TT-1))*FF + 0];
    }

    f32x4 acc[2][4];
#pragma unroll
    for (int g = 0; g < 4; ++g){
      f32x4 v = {bias1[g], bias1[g], bias1[g], bias1[g]};
      acc[0][g] = v; acc[1][g] = v;
    }
#pragma unroll
    for (int ks = 0; ks < 8; ++ks){
      const int colA = ks*32 + 8*lhi;
      f16x8 a0 = *(const f16x8*)&Rb[(l15)*PITCH + colA];
      f16x8 a1 = *(const f16x8*)&Rb[(16 + l15)*PITCH + colA];
#pragma unroll
      for (int g = 0; g < 4; ++g){
        f16x8 bf;
        if (ks < 5) bf = wr[5 + ks][g];
        else        bf = *(const f16x8*)&wlds[(((ks-5)*512) + g*128 + jc)*WP + lhi*8];
        acc[0][g] = __builtin_amdgcn_mfma_f32_16x16x32_f16(a0, bf, acc[0][g], 0, 0, 0);
        acc[1][g] = __builtin_amdgcn_mfma_f32_16x16x32_f16(a1, bf, acc[1][g], 0, 0, 0);
      }
    }
#pragma unroll
    for (int m = 0; m < 2; ++m)
#pragma unroll
      for (int r = 0; r < 4; ++r){
        float h = cell_elem(acc[m][0][r], acc[m][1][r], acc[m][2][r], acc[m][3][r], cs1[m*4+r]);
        Qb[(m*16 + lhi*4 + r)*PITCH + 128 + jc] = (f16)h;
      }
    __syncthreads();

    {
      const int dof = (l >> 5) * 64;
      const f16*  hp = &Qb[(l & 31)*PITCH + 128 + dof];
      const float* fp = &fcw_s[dof];
      float s0 = 0.f, s1 = 0.f;
#pragma unroll
      for (int c = 0; c < 4; ++c){
        f16x8 hv = *(const f16x8*)(hp + c*16);
        f16x8 gv = *(const f16x8*)(hp + c*16 + 8);
#pragma unroll
        for (int u = 0; u < 8; ++u){
          s0 += (float)hv[u] * fp[c*16 + u];
          s1 += (float)gv[u] * fp[c*16 + 8 + u];
        }
      }
      float s = s0 + s1;
      s += __shfl_xor(s, 32);
      ddv = s + fcb0;
    }
    if (w == 0 && l < 32){
      pnl += (dold - ddv) * price_r;
      dbuf[l][15] = ddv;              // col 512
      pnlbuf[l] = pnl + ddv*lastp;
    }
    __syncthreads();
  }

  // final flush (out cols 497..512) and pnl
  __builtin_nontemporal_store(dbuf[tid>>4][tid&15],
      &out[(size_t)(bg0 + (tid>>4))*513 + 497 + (tid&15)]);
  if (tid < BC)
    out[(size_t)BB*513 + bg0 + tid] = pnlbuf[tid] + PnL[bg0 + tid];
}

extern "C" void kernel_launch(void* const* d_in, const int* in_sizes, int n_in,
                              void* d_out, int out_size, void* d_ws, size_t ws_size,
                              hipStream_t stream)
{
  const float* data = (const float*)d_in[0];
  const float* PnL  = (const float*)d_in[1];
  const float* Wih0 = (const float*)d_in[2];
  const float* Whh0 = (const float*)d_in[3];
  const float* bih0 = (const float*)d_in[4];
  const float* bhh0 = (const float*)d_in[5];
  const float* Wih1 = (const float*)d_in[6];
  const float* Whh1 = (const float*)d_in[7];
  const float* bih1 = (const float*)d_in[8];
  const float* bhh1 = (const float*)d_in[9];
  const float* fcW  = (const float*)d_in[10];
  const float* fcb  = (const float*)d_in[11];
  const int*   ploc = (const int*)d_in[12];

  f16*   Bp      = (f16*)d_ws;
  float* biasSum = (float*)((char*)d_ws + WS_BIAS_OFF);
  float* out     = (float*)d_out;

  const int prepN = NBP + 1024;
  prep_kernel<<<(prepN + 255)/256, 256, 0, stream>>>(
      Wih0, Whh0, bih0, bhh0, Wih1, Whh1, bih1, bhh1, Bp, biasSum);
  lstm_kernel<<<BB/BC, NTH, 0, stream>>>(
      data, PnL, Bp, biasSum, fcW, fcb, ploc, Wih0, out);
}